// Round 1
// baseline (750.265 us; speedup 1.0000x reference)
//
#include <hip/hip_runtime.h>

#define C0 10000
#define C1 30000
#define C2 50000

typedef __attribute__((ext_vector_type(8))) short short8;
typedef __attribute__((ext_vector_type(4))) float f32x4;

__device__ __forceinline__ unsigned short f2bf(float f) {
    unsigned int u = __float_as_uint(f);
    u += 0x7FFF + ((u >> 16) & 1);   // round-to-nearest-even
    return (unsigned short)(u >> 16);
}

#define BM 128
#define BN 128
#define BK 64
#define LDT (BK + 8)   // 72 ushorts -> 144 B row stride, 16B-aligned, 2-way-max bank alias

// C[M,N] = A[M,K] * B[N,K]^T  (bf16 MFMA, f32 accumulate)
// A: [M,K] f32 row-major (M = 4096, multiple of BM; K multiple of BK)
// B: [Nn,K] f32 row-major; rows >= Nn treated as zero
// C: [M,Nn] f32 row-major
// maskMode: 0 none, 1 zero rows unless target in [C0,C1), 2 zero rows unless target in [C1,C2)
__global__ __launch_bounds__(256) void gemm_bt(
    const float* __restrict__ A, const float* __restrict__ B,
    float* __restrict__ C, int Nn, int K,
    const int* __restrict__ target, int maskMode)
{
    __shared__ unsigned short As[BM * LDT];
    __shared__ unsigned short Bs[BN * LDT];

    const int t    = threadIdx.x;
    const int lane = t & 63;
    const int w    = t >> 6;        // wave 0..3
    const int wr   = w >> 1;        // wave row (2)
    const int wc   = w & 1;         // wave col (2)
    const int mBase = blockIdx.y * BM;
    const int nBase = blockIdx.x * BN;

    const int tr = t >> 4;          // 0..15 (row group for staging)
    const int tc = t & 15;          // 0..15 (float4 column for staging)

    f32x4 acc[4][4] = {};

    for (int k0 = 0; k0 < K; k0 += BK) {
        // ---- stage A tile: 128 rows x 64 cols f32 -> bf16 LDS ----
        #pragma unroll
        for (int j = 0; j < 8; j++) {
            int row = j * 16 + tr;
            float4 v = *((const float4*)(A + (size_t)(mBase + row) * K + k0) + tc);
            ushort4 b;
            b.x = f2bf(v.x); b.y = f2bf(v.y); b.z = f2bf(v.z); b.w = f2bf(v.w);
            *(ushort4*)(&As[row * LDT + tc * 4]) = b;
        }
        // ---- stage B tile (rows may exceed Nn -> zeros) ----
        #pragma unroll
        for (int j = 0; j < 8; j++) {
            int row = j * 16 + tr;
            int gn = nBase + row;
            ushort4 b;
            if (gn < Nn) {
                float4 v = *((const float4*)(B + (size_t)gn * K + k0) + tc);
                b.x = f2bf(v.x); b.y = f2bf(v.y); b.z = f2bf(v.z); b.w = f2bf(v.w);
            } else {
                b.x = 0; b.y = 0; b.z = 0; b.w = 0;
            }
            *(ushort4*)(&Bs[row * LDT + tc * 4]) = b;
        }
        __syncthreads();

        // ---- MFMA: each wave computes a 64x64 sub-tile as 4x4 fragments ----
        #pragma unroll
        for (int kk = 0; kk < BK / 32; kk++) {
            const int kOff = kk * 32 + (lane >> 4) * 8;
            short8 af[4], bf[4];
            #pragma unroll
            for (int m = 0; m < 4; m++) {
                int row = wr * 64 + m * 16 + (lane & 15);
                af[m] = *(const short8*)(&As[row * LDT + kOff]);
            }
            #pragma unroll
            for (int n = 0; n < 4; n++) {
                int row = wc * 64 + n * 16 + (lane & 15);
                bf[n] = *(const short8*)(&Bs[row * LDT + kOff]);
            }
            #pragma unroll
            for (int m = 0; m < 4; m++)
                #pragma unroll
                for (int n = 0; n < 4; n++)
                    acc[m][n] = __builtin_amdgcn_mfma_f32_16x16x32_bf16(
                        af[m], bf[n], acc[m][n], 0, 0, 0);
        }
        __syncthreads();
    }

    // ---- epilogue: D row = (lane>>4)*4 + i, col = lane&15 (m89-verified) ----
    #pragma unroll
    for (int m = 0; m < 4; m++) {
        #pragma unroll
        for (int i = 0; i < 4; i++) {
            int grow = mBase + wr * 64 + m * 16 + (lane >> 4) * 4 + i;
            float s = 1.0f;
            if (maskMode) {
                int tg = target[grow];
                bool in = (maskMode == 1) ? (tg >= C0 && tg < C1)
                                          : (tg >= C1 && tg < C2);
                s = in ? 1.0f : 0.0f;
            }
            #pragma unroll
            for (int n = 0; n < 4; n++) {
                int gcol = nBase + wc * 64 + n * 16 + (lane & 15);
                if (gcol < Nn)
                    C[(size_t)grow * Nn + gcol] = acc[m][n][i] * s;
            }
        }
    }
}

__global__ void routing_kernel(const int* __restrict__ target,
                               float* __restrict__ o3, float* __restrict__ o4,
                               float* __restrict__ o5, int N)
{
    int i = blockIdx.x * blockDim.x + threadIdx.x;
    if (i < N) {
        int tg = target[i];
        bool m0 = (tg >= C0) && (tg < C1);
        bool m1 = (tg >= C1) && (tg < C2);
        o3[i] = (float)(m0 ? C0 : (m1 ? (C0 + 1) : tg));
        o4[i] = (float)(m0 ? (tg - C0) : 0);
        o5[i] = (float)(m1 ? (tg - C1) : 0);
    }
}

extern "C" void kernel_launch(void* const* d_in, const int* in_sizes, int n_in,
                              void* d_out, int out_size, void* d_ws, size_t ws_size,
                              hipStream_t stream)
{
    const float* input   = (const float*)d_in[0];   // [2,2048,1024]
    const int*   target  = (const int*)  d_in[1];   // [2,2048]
    const float* head_w  = (const float*)d_in[2];   // [10002,1024]
    const float* proj0_w = (const float*)d_in[3];   // [256,1024]
    const float* out0_w  = (const float*)d_in[4];   // [20000,256]
    const float* proj1_w = (const float*)d_in[5];   // [64,1024]
    const float* out1_w  = (const float*)d_in[6];   // [20000,64]

    const int N = 4096;

    float* out      = (float*)d_out;
    float* head_out = out;                                   // [4096,10002]
    float* tail0    = head_out + (size_t)N * 10002;          // [4096,20000]
    float* tail1    = tail0 + (size_t)N * 20000;             // [4096,20000]
    float* o3       = tail1 + (size_t)N * 20000;             // [4096]
    float* o4       = o3 + N;
    float* o5       = o4 + N;

    float* p0 = (float*)d_ws;                 // [4096,256] f32 = 4 MB
    float* p1 = p0 + (size_t)N * 256;         // [4096,64]  f32 = 1 MB

    routing_kernel<<<dim3((N + 255) / 256), dim3(256), 0, stream>>>(target, o3, o4, o5, N);

    dim3 blk(256);
    // head: N=10002, K=1024
    gemm_bt<<<dim3((10002 + BN - 1) / BN, N / BM), blk, 0, stream>>>(
        input, head_w, head_out, 10002, 1024, nullptr, 0);
    // proj0: N=256, K=1024 -> p0
    gemm_bt<<<dim3((256 + BN - 1) / BN, N / BM), blk, 0, stream>>>(
        input, proj0_w, p0, 256, 1024, nullptr, 0);
    // proj1: N=64, K=1024 -> p1
    gemm_bt<<<dim3(1, N / BM), blk, 0, stream>>>(
        input, proj1_w, p1, 64, 1024, nullptr, 0);
    // tail0: A=p0 [4096,256], B=out0_w [20000,256], mask band 0
    gemm_bt<<<dim3((20000 + BN - 1) / BN, N / BM), blk, 0, stream>>>(
        p0, out0_w, tail0, 20000, 256, target, 1);
    // tail1: A=p1 [4096,64], B=out1_w [20000,64], mask band 1
    gemm_bt<<<dim3((20000 + BN - 1) / BN, N / BM), blk, 0, stream>>>(
        p1, out1_w, tail1, 20000, 64, target, 2);
}

// Round 2
// 444.358 us; speedup vs baseline: 1.6884x; 1.6884x over previous
//
#include <hip/hip_runtime.h>

#define C0 10000
#define C1 30000
#define C2 50000

typedef __attribute__((ext_vector_type(8))) short short8;
typedef __attribute__((ext_vector_type(8))) unsigned short ushort8;
typedef __attribute__((ext_vector_type(4))) float f32x4;

__device__ __forceinline__ unsigned short f2bf(float f) {
    unsigned int u = __float_as_uint(f);
    u += 0x7FFF + ((u >> 16) & 1);   // round-to-nearest-even
    return (unsigned short)(u >> 16);
}

// ---------------- ws layout (bf16 elements) ----------------
#define SZ_IN    (4096 * 1024)
#define OFF_IN   0
#define HW_ROWSP 10112                 // 79 * 128
#define SZ_HW    (HW_ROWSP * 1024)
#define REAL_HW  (10002 * 1024)
#define OFF_HW   (OFF_IN + SZ_IN)
#define SZ_P0W   (256 * 1024)
#define OFF_P0W  (OFF_HW + SZ_HW)
#define O0_ROWSP 20096                 // 157 * 128
#define SZ_O0    (O0_ROWSP * 256)
#define REAL_O0  (20000 * 256)
#define OFF_O0   (OFF_P0W + SZ_P0W)
#define SZ_P1W   (64 * 1024)
#define OFF_P1W  (OFF_O0 + SZ_O0)
#define O1_ROWSP 20096
#define SZ_O1    (O1_ROWSP * 64)
#define REAL_O1  (20000 * 64)
#define OFF_O1   (OFF_P1W + SZ_P1W)
#define CVT_TOTAL (OFF_O1 + SZ_O1)     // everything before is converted from f32
#define OFF_PP0  CVT_TOTAL             // p0 bf16 [4096,256]
#define SZ_PP0   (4096 * 256)
#define OFF_PP1  (OFF_PP0 + SZ_PP0)    // p1 bf16 [4096,64]
#define SZ_PP1   (4096 * 64)

// f32 -> bf16 conversion of all operands into ws, with zero row-padding.
__global__ __launch_bounds__(256) void convert_kernel(
    const float* __restrict__ in,  const float* __restrict__ hw,
    const float* __restrict__ p0w, const float* __restrict__ o0w,
    const float* __restrict__ p1w, const float* __restrict__ o1w,
    unsigned short* __restrict__ ws)
{
    long long i = ((long long)blockIdx.x * blockDim.x + threadIdx.x) * 8;
    if (i >= CVT_TOTAL) return;
    const float* src;
    long long rel, real;
    if (i < OFF_HW)       { src = in;  rel = i - OFF_IN;  real = SZ_IN;   }
    else if (i < OFF_P0W) { src = hw;  rel = i - OFF_HW;  real = REAL_HW; }
    else if (i < OFF_O0)  { src = p0w; rel = i - OFF_P0W; real = SZ_P0W;  }
    else if (i < OFF_P1W) { src = o0w; rel = i - OFF_O0;  real = REAL_O0; }
    else if (i < OFF_O1)  { src = p1w; rel = i - OFF_P1W; real = SZ_P1W;  }
    else                  { src = o1w; rel = i - OFF_O1;  real = REAL_O1; }
    ushort8 o;
    if (rel < real) {
        float4 v0 = *(const float4*)(src + rel);
        float4 v1 = *(const float4*)(src + rel + 4);
        o[0] = f2bf(v0.x); o[1] = f2bf(v0.y); o[2] = f2bf(v0.z); o[3] = f2bf(v0.w);
        o[4] = f2bf(v1.x); o[5] = f2bf(v1.y); o[6] = f2bf(v1.z); o[7] = f2bf(v1.w);
    } else {
        o = (ushort8)0;
    }
    *(ushort8*)(ws + i) = o;
}

#define BM 128
#define BN 128
#define BK 64

// C[M,Nn] = A[M,K] * B[Npad,K]^T, bf16 inputs (ws), f32 accum.
// Staging: global_load_lds width 16, linear LDS (m97 structure).
// MASK: 0 none; 1 zero row unless target in [C0,C1); 2 unless [C1,C2).
// OUTBF: write C as bf16 (proj outputs) instead of f32.
template<int MASK, bool OUTBF>
__global__ __launch_bounds__(256) void gemm_lds(
    const unsigned short* __restrict__ A,
    const unsigned short* __restrict__ B,
    void* __restrict__ Cv, int Nn, int K,
    const int* __restrict__ target)
{
    __shared__ unsigned short As[BM * BK];   // 16 KB
    __shared__ unsigned short Bs[BN * BK];   // 16 KB

    const int t    = threadIdx.x;
    const int lane = t & 63;
    const int w    = t >> 6;
    const int wr   = w >> 1;
    const int wc   = w & 1;
    const int mBase = blockIdx.y * BM;
    const int nBase = blockIdx.x * BN;

    const int srow = lane >> 3;         // 0..7  (row within 8-row chunk)
    const int scol = (lane & 7) * 8;    // element col (16B chunks)

    f32x4 acc[4][4] = {};

    for (int k0 = 0; k0 < K; k0 += BK) {
        // each wave stages rows [w*32, w*32+32) of A and B: 4 calls x 8 rows
        #pragma unroll
        for (int c = 0; c < 4; c++) {
            const int rbase = w * 32 + c * 8;
            const unsigned short* ga = A + (size_t)(mBase + rbase + srow) * K + k0 + scol;
            __builtin_amdgcn_global_load_lds(
                (const __attribute__((address_space(1))) void*)ga,
                (__attribute__((address_space(3))) void*)&As[rbase * BK],
                16, 0, 0);
            const unsigned short* gb = B + (size_t)(nBase + rbase + srow) * K + k0 + scol;
            __builtin_amdgcn_global_load_lds(
                (const __attribute__((address_space(1))) void*)gb,
                (__attribute__((address_space(3))) void*)&Bs[rbase * BK],
                16, 0, 0);
        }
        __syncthreads();

        #pragma unroll
        for (int kk = 0; kk < BK / 32; kk++) {
            const int kOff = kk * 32 + (lane >> 4) * 8;
            short8 af[4], bf[4];
            #pragma unroll
            for (int m = 0; m < 4; m++)
                af[m] = *(const short8*)(&As[(wr * 64 + m * 16 + (lane & 15)) * BK + kOff]);
            #pragma unroll
            for (int n = 0; n < 4; n++)
                bf[n] = *(const short8*)(&Bs[(wc * 64 + n * 16 + (lane & 15)) * BK + kOff]);
            #pragma unroll
            for (int m = 0; m < 4; m++)
                #pragma unroll
                for (int n = 0; n < 4; n++)
                    acc[m][n] = __builtin_amdgcn_mfma_f32_16x16x32_bf16(
                        af[m], bf[n], acc[m][n], 0, 0, 0);
        }
        __syncthreads();
    }

    #pragma unroll
    for (int m = 0; m < 4; m++) {
        #pragma unroll
        for (int i = 0; i < 4; i++) {
            int grow = mBase + wr * 64 + m * 16 + (lane >> 4) * 4 + i;
            float s = 1.0f;
            if (MASK) {
                int tg = target[grow];
                bool in = (MASK == 1) ? (tg >= C0 && tg < C1)
                                      : (tg >= C1 && tg < C2);
                s = in ? 1.0f : 0.0f;
            }
            #pragma unroll
            for (int n = 0; n < 4; n++) {
                int gcol = nBase + wc * 64 + n * 16 + (lane & 15);
                if (gcol < Nn) {
                    float v = acc[m][n][i] * s;
                    if (OUTBF)
                        ((unsigned short*)Cv)[(size_t)grow * Nn + gcol] = f2bf(v);
                    else
                        ((float*)Cv)[(size_t)grow * Nn + gcol] = v;
                }
            }
        }
    }
}

__global__ void routing_kernel(const int* __restrict__ target,
                               float* __restrict__ o3, float* __restrict__ o4,
                               float* __restrict__ o5, int N)
{
    int i = blockIdx.x * blockDim.x + threadIdx.x;
    if (i < N) {
        int tg = target[i];
        bool m0 = (tg >= C0) && (tg < C1);
        bool m1 = (tg >= C1) && (tg < C2);
        o3[i] = (float)(m0 ? C0 : (m1 ? (C0 + 1) : tg));
        o4[i] = (float)(m0 ? (tg - C0) : 0);
        o5[i] = (float)(m1 ? (tg - C1) : 0);
    }
}

extern "C" void kernel_launch(void* const* d_in, const int* in_sizes, int n_in,
                              void* d_out, int out_size, void* d_ws, size_t ws_size,
                              hipStream_t stream)
{
    const float* input   = (const float*)d_in[0];
    const int*   target  = (const int*)  d_in[1];
    const float* head_w  = (const float*)d_in[2];
    const float* proj0_w = (const float*)d_in[3];
    const float* out0_w  = (const float*)d_in[4];
    const float* proj1_w = (const float*)d_in[5];
    const float* out1_w  = (const float*)d_in[6];

    const int N = 4096;

    float* out      = (float*)d_out;
    float* head_out = out;
    float* tail0    = head_out + (size_t)N * 10002;
    float* tail1    = tail0 + (size_t)N * 20000;
    float* o3       = tail1 + (size_t)N * 20000;
    float* o4       = o3 + N;
    float* o5       = o4 + N;

    unsigned short* ws = (unsigned short*)d_ws;
    unsigned short* in_bf  = ws + OFF_IN;
    unsigned short* hw_bf  = ws + OFF_HW;
    unsigned short* p0w_bf = ws + OFF_P0W;
    unsigned short* o0w_bf = ws + OFF_O0;
    unsigned short* p1w_bf = ws + OFF_P1W;
    unsigned short* o1w_bf = ws + OFF_O1;
    unsigned short* pp0    = ws + OFF_PP0;
    unsigned short* pp1    = ws + OFF_PP1;

    // 1. convert everything to bf16 (with zero row-padding for weights)
    convert_kernel<<<dim3(CVT_TOTAL / 8 / 256), dim3(256), 0, stream>>>(
        input, head_w, proj0_w, out0_w, proj1_w, out1_w, ws);

    // 2. routing outputs
    routing_kernel<<<dim3((N + 255) / 256), dim3(256), 0, stream>>>(target, o3, o4, o5, N);

    dim3 blk(256);
    // 3. head: [4096,1024] x [10112,1024]^T -> f32 [4096,10002]
    gemm_lds<0, false><<<dim3(HW_ROWSP / BN, N / BM), blk, 0, stream>>>(
        in_bf, hw_bf, head_out, 10002, 1024, nullptr);
    // 4. proj0 -> bf16 p0 [4096,256]
    gemm_lds<0, true><<<dim3(256 / BN, N / BM), blk, 0, stream>>>(
        in_bf, p0w_bf, pp0, 256, 1024, nullptr);
    // 5. proj1 -> bf16 p1 [4096,64]  (B rows 64..127 read garbage, cols guarded)
    gemm_lds<0, true><<<dim3(1, N / BM), blk, 0, stream>>>(
        in_bf, p1w_bf, pp1, 64, 1024, nullptr);
    // 6. tail0: p0 x out0_w^T, masked band 0 -> f32 [4096,20000]
    gemm_lds<1, false><<<dim3(O0_ROWSP / BN, N / BM), blk, 0, stream>>>(
        pp0, o0w_bf, tail0, 20000, 256, target);
    // 7. tail1: p1 x out1_w^T, masked band 1 -> f32 [4096,20000]
    gemm_lds<2, false><<<dim3(O1_ROWSP / BN, N / BM), blk, 0, stream>>>(
        pp1, o1w_bf, tail1, 20000, 64, target);
}

// Round 3
// 398.402 us; speedup vs baseline: 1.8832x; 1.1154x over previous
//
#include <hip/hip_runtime.h>

#define C0 10000
#define C1 30000
#define C2 50000

typedef __attribute__((ext_vector_type(8))) short short8;
typedef __attribute__((ext_vector_type(8))) unsigned short ushort8;
typedef __attribute__((ext_vector_type(4))) float f32x4;

__device__ __forceinline__ unsigned short f2bf(float f) {
    unsigned int u = __float_as_uint(f);
    u += 0x7FFF + ((u >> 16) & 1);   // round-to-nearest-even
    return (unsigned short)(u >> 16);
}

// ---------------- ws layout (bf16 elements) ----------------
#define SZ_IN    (4096 * 1024)
#define OFF_IN   0
#define HW_ROWSP 10240                 // 40 * 256 (for 256-wide tiles)
#define SZ_HW    (HW_ROWSP * 1024)
#define REAL_HW  (10002 * 1024)
#define OFF_HW   (OFF_IN + SZ_IN)
// merged proj weights: [384,1024]: rows 0-255 proj0_w, 256-319 proj1_w, 320-383 zero
#define OFF_PJ   (OFF_HW + SZ_HW)
#define SZ_PJ    (384 * 1024)
#define PJ_P0    (256 * 1024)
#define PJ_P1    (64 * 1024)
#define O0_ROWSP 20096                 // 157 * 128
#define SZ_O0    (O0_ROWSP * 256)
#define REAL_O0  (20000 * 256)
#define OFF_O0   (OFF_PJ + SZ_PJ)
#define O1_ROWSP 20096
#define SZ_O1    (O1_ROWSP * 64)
#define REAL_O1  (20000 * 64)
#define OFF_O1   (OFF_O0 + SZ_O0)
#define CVT_TOTAL (OFF_O1 + SZ_O1)
#define OFF_PP   CVT_TOTAL             // pp bf16 [4096, 320] (cols 0-255 = p0, 256-319 = p1)
#define SZ_PP    (4096 * 320)

// f32 -> bf16 conversion of all operands into ws (zero row-padding), + routing outputs.
__global__ __launch_bounds__(256) void convert_kernel(
    const float* __restrict__ in,  const float* __restrict__ hw,
    const float* __restrict__ p0w, const float* __restrict__ o0w,
    const float* __restrict__ p1w, const float* __restrict__ o1w,
    unsigned short* __restrict__ ws,
    const int* __restrict__ target,
    float* __restrict__ o3, float* __restrict__ o4, float* __restrict__ o5)
{
    long long tid = (long long)blockIdx.x * blockDim.x + threadIdx.x;
    // fold routing outputs (4096 tokens) into this kernel
    if (tid < 4096) {
        int tg = target[tid];
        bool m0 = (tg >= C0) && (tg < C1);
        bool m1 = (tg >= C1) && (tg < C2);
        o3[tid] = (float)(m0 ? C0 : (m1 ? (C0 + 1) : tg));
        o4[tid] = (float)(m0 ? (tg - C0) : 0);
        o5[tid] = (float)(m1 ? (tg - C1) : 0);
    }
    long long i = tid * 8;
    if (i >= CVT_TOTAL) return;
    const float* src;
    long long rel, real;
    if (i < OFF_HW)                 { src = in;  rel = i - OFF_IN;              real = SZ_IN;   }
    else if (i < OFF_PJ)            { src = hw;  rel = i - OFF_HW;              real = REAL_HW; }
    else if (i < OFF_PJ + PJ_P0)    { src = p0w; rel = i - OFF_PJ;              real = PJ_P0;   }
    else if (i < OFF_PJ + PJ_P0 + PJ_P1) { src = p1w; rel = i - (OFF_PJ + PJ_P0); real = PJ_P1; }
    else if (i < OFF_O0)            { src = p1w; rel = 1;                       real = 0;       }
    else if (i < OFF_O1)            { src = o0w; rel = i - OFF_O0;              real = REAL_O0; }
    else                            { src = o1w; rel = i - OFF_O1;              real = REAL_O1; }
    ushort8 o;
    if (rel < real) {
        float4 v0 = *(const float4*)(src + rel);
        float4 v1 = *(const float4*)(src + rel + 4);
        o[0] = f2bf(v0.x); o[1] = f2bf(v0.y); o[2] = f2bf(v0.z); o[3] = f2bf(v0.w);
        o[4] = f2bf(v1.x); o[5] = f2bf(v1.y); o[6] = f2bf(v1.z); o[7] = f2bf(v1.w);
    } else {
        o = (ushort8)0;
    }
    *(ushort8*)(ws + i) = o;
}

// ================= 256x256 8-wave phase-split GEMM (head) =================
// C[M,Nn] = A[M,K] * B[Npad,K]^T, bf16 in ws, f32 out. BK=64.
// 2-buffer LDS (128 KB), burst staging of K-tile t+1 with counted vmcnt(8),
// raw s_barriers (no vmcnt-0 drain), 4 MFMA phases per K-tile, setprio,
// XOR-swizzled LDS (slot ^= row&7) with pre-swizzled global source.

__device__ __forceinline__ short8 lds_read_swz(const unsigned short* base, int row, int chunk) {
    int slot = chunk ^ (row & 7);
    return *(const short8*)(base + row * 64 + slot * 8);
}

#define PHASE(MO, NO, LOADA)                                                   \
  {                                                                            \
    if (LOADA) {                                                               \
      _Pragma("unroll") for (int m = 0; m < 4; m++)                            \
        _Pragma("unroll") for (int ks = 0; ks < 2; ks++)                       \
          af[m][ks] = lds_read_swz(Ab, (MO + m) * 16 + lr, ks * 4 + lq);       \
    }                                                                          \
    _Pragma("unroll") for (int n = 0; n < 2; n++)                              \
      _Pragma("unroll") for (int ks = 0; ks < 2; ks++)                         \
        bfrag[n][ks] = lds_read_swz(Bb, brow0 + (NO + n) * 16 + lr, ks * 4 + lq); \
    __builtin_amdgcn_s_barrier();                                              \
    asm volatile("s_waitcnt lgkmcnt(0)" ::: "memory");                         \
    __builtin_amdgcn_sched_barrier(0);                                         \
    __builtin_amdgcn_s_setprio(1);                                             \
    _Pragma("unroll") for (int m = 0; m < 4; m++)                              \
      _Pragma("unroll") for (int n = 0; n < 2; n++)                            \
        _Pragma("unroll") for (int ks = 0; ks < 2; ks++)                       \
          acc[MO + m][NO + n] = __builtin_amdgcn_mfma_f32_16x16x32_bf16(       \
              af[m][ks], bfrag[n][ks], acc[MO + m][NO + n], 0, 0, 0);          \
    __builtin_amdgcn_s_setprio(0);                                             \
    __builtin_amdgcn_s_barrier();                                              \
  }

#define STAGE(bufi, kofs)                                                      \
  {                                                                            \
    _Pragma("unroll") for (int hh = 0; hh < 2; hh++)                           \
      _Pragma("unroll") for (int cc = 0; cc < 2; cc++) {                       \
        __builtin_amdgcn_global_load_lds(                                      \
            (const __attribute__((address_space(1))) void*)(srcA[hh][cc] + (kofs)), \
            (__attribute__((address_space(3))) void*)(lds + (bufi) * 32768 +   \
                hh * 8192 + (cc * 64 + w * 8) * 64), 16, 0, 0);                \
        __builtin_amdgcn_global_load_lds(                                      \
            (const __attribute__((address_space(1))) void*)(srcB[hh][cc] + (kofs)), \
            (__attribute__((address_space(3))) void*)(lds + (bufi) * 32768 +   \
                16384 + hh * 8192 + (cc * 64 + w * 8) * 64), 16, 0, 0);        \
      }                                                                        \
  }

__global__ __launch_bounds__(512) void gemm256(
    const unsigned short* __restrict__ A,
    const unsigned short* __restrict__ B,
    float* __restrict__ C, int Nn, int K, int NT)
{
    __shared__ unsigned short lds[65536];   // 128 KB: [buf2][op2][half2][128*64]

    const int t    = threadIdx.x;
    const int lane = t & 63;
    const int w    = t >> 6;        // wave 0..7
    const int wm   = w >> 2;        // 0..1  -> A half
    const int wn   = w & 3;         // 0..3  -> B cols wn*64
    const int lr   = lane & 15;
    const int lq   = lane >> 4;
    const int brow0 = (wn & 1) * 64;

    const int mBase = blockIdx.y * 256;
    const int nBase = blockIdx.x * 256;

    // pre-swizzled per-lane staging sources (rule #21: linear LDS dest + swz source)
    const int lr3 = lane >> 3;
    const int swzc = ((lane & 7) ^ lr3) * 8;
    const unsigned short* srcA[2][2];
    const unsigned short* srcB[2][2];
    #pragma unroll
    for (int hh = 0; hh < 2; hh++)
        #pragma unroll
        for (int cc = 0; cc < 2; cc++) {
            int rrow = hh * 128 + cc * 64 + w * 8 + lr3;
            srcA[hh][cc] = A + (size_t)(mBase + rrow) * K + swzc;
            srcB[hh][cc] = B + (size_t)(nBase + rrow) * K + swzc;
        }

    f32x4 acc[8][4] = {};
    short8 af[4][2], bfrag[2][2];

    STAGE(0, 0);                                    // prologue: K-tile 0
    for (int kt = 0; kt < NT; ++kt) {
        const int buf = kt & 1;
        STAGE(buf ^ 1, (kt + 1) * 64);              // prefetch next K-tile (dummy at last)
        asm volatile("s_waitcnt vmcnt(8)" ::: "memory");  // counted: tile kt done, next in flight
        __builtin_amdgcn_s_barrier();
        const unsigned short* Ab = lds + buf * 32768 + wm * 8192;
        const unsigned short* Bb = lds + buf * 32768 + 16384 + (wn >> 1) * 8192;
        PHASE(0, 0, 1)
        PHASE(0, 2, 0)
        PHASE(4, 0, 1)
        PHASE(4, 2, 0)
    }

    // epilogue: wave writes rows [wm*128,+128), cols [wn*64,+64)
    #pragma unroll
    for (int m = 0; m < 8; m++) {
        #pragma unroll
        for (int i = 0; i < 4; i++) {
            int grow = mBase + wm * 128 + m * 16 + lq * 4 + i;
            #pragma unroll
            for (int n = 0; n < 4; n++) {
                int gcol = nBase + wn * 64 + n * 16 + lr;
                if (gcol < Nn)
                    C[(size_t)grow * Nn + gcol] = acc[m][n][i];
            }
        }
    }
}

// ================= 128x128 GEMM (projs + tails), m97 structure =================
#define BM 128
#define BN 128
#define BK 64

template<int MASK, bool OUTBF>
__global__ __launch_bounds__(256) void gemm_lds(
    const unsigned short* __restrict__ A, int lda,
    const unsigned short* __restrict__ B,
    void* __restrict__ Cv, int Nn, int K,
    const int* __restrict__ target)
{
    __shared__ unsigned short As[BM * BK];
    __shared__ unsigned short Bs[BN * BK];

    const int t    = threadIdx.x;
    const int lane = t & 63;
    const int w    = t >> 6;
    const int wr   = w >> 1;
    const int wc   = w & 1;
    const int mBase = blockIdx.y * BM;
    const int nBase = blockIdx.x * BN;

    const int srow = lane >> 3;
    const int scol = (lane & 7) * 8;

    f32x4 acc[4][4] = {};

    for (int k0 = 0; k0 < K; k0 += BK) {
        #pragma unroll
        for (int c = 0; c < 4; c++) {
            const int rbase = w * 32 + c * 8;
            const unsigned short* ga = A + (size_t)(mBase + rbase + srow) * lda + k0 + scol;
            __builtin_amdgcn_global_load_lds(
                (const __attribute__((address_space(1))) void*)ga,
                (__attribute__((address_space(3))) void*)&As[rbase * BK], 16, 0, 0);
            const unsigned short* gb = B + (size_t)(nBase + rbase + srow) * K + k0 + scol;
            __builtin_amdgcn_global_load_lds(
                (const __attribute__((address_space(1))) void*)gb,
                (__attribute__((address_space(3))) void*)&Bs[rbase * BK], 16, 0, 0);
        }
        __syncthreads();

        #pragma unroll
        for (int kk = 0; kk < BK / 32; kk++) {
            const int kOff = kk * 32 + (lane >> 4) * 8;
            short8 a4[4], b4[4];
            #pragma unroll
            for (int m = 0; m < 4; m++)
                a4[m] = *(const short8*)(&As[(wr * 64 + m * 16 + (lane & 15)) * BK + kOff]);
            #pragma unroll
            for (int n = 0; n < 4; n++)
                b4[n] = *(const short8*)(&Bs[(wc * 64 + n * 16 + (lane & 15)) * BK + kOff]);
            #pragma unroll
            for (int m = 0; m < 4; m++)
                #pragma unroll
                for (int n = 0; n < 4; n++)
                    acc[m][n] = __builtin_amdgcn_mfma_f32_16x16x32_bf16(
                        a4[m], b4[n], acc[m][n], 0, 0, 0);
        }
        __syncthreads();
    }

    #pragma unroll
    for (int m = 0; m < 4; m++) {
        #pragma unroll
        for (int i = 0; i < 4; i++) {
            int grow = mBase + wr * 64 + m * 16 + (lane >> 4) * 4 + i;
            float s = 1.0f;
            if (MASK) {
                int tg = target[grow];
                bool in = (MASK == 1) ? (tg >= C0 && tg < C1)
                                      : (tg >= C1 && tg < C2);
                s = in ? 1.0f : 0.0f;
            }
            #pragma unroll
            for (int n = 0; n < 4; n++) {
                int gcol = nBase + wc * 64 + n * 16 + (lane & 15);
                if (gcol < Nn) {
                    float v = acc[m][n][i] * s;
                    if (OUTBF)
                        ((unsigned short*)Cv)[(size_t)grow * Nn + gcol] = f2bf(v);
                    else
                        ((float*)Cv)[(size_t)grow * Nn + gcol] = v;
                }
            }
        }
    }
}

extern "C" void kernel_launch(void* const* d_in, const int* in_sizes, int n_in,
                              void* d_out, int out_size, void* d_ws, size_t ws_size,
                              hipStream_t stream)
{
    const float* input   = (const float*)d_in[0];
    const int*   target  = (const int*)  d_in[1];
    const float* head_w  = (const float*)d_in[2];
    const float* proj0_w = (const float*)d_in[3];
    const float* out0_w  = (const float*)d_in[4];
    const float* proj1_w = (const float*)d_in[5];
    const float* out1_w  = (const float*)d_in[6];

    const int N = 4096;

    float* out      = (float*)d_out;
    float* head_out = out;
    float* tail0    = head_out + (size_t)N * 10002;
    float* tail1    = tail0 + (size_t)N * 20000;
    float* o3       = tail1 + (size_t)N * 20000;
    float* o4       = o3 + N;
    float* o5       = o4 + N;

    unsigned short* ws = (unsigned short*)d_ws;
    unsigned short* in_bf  = ws + OFF_IN;
    unsigned short* hw_bf  = ws + OFF_HW;
    unsigned short* pjw_bf = ws + OFF_PJ;
    unsigned short* o0w_bf = ws + OFF_O0;
    unsigned short* o1w_bf = ws + OFF_O1;
    unsigned short* pp     = ws + OFF_PP;

    // 1. convert all operands to bf16 (zero-padded) + routing outputs
    convert_kernel<<<dim3(CVT_TOTAL / 8 / 256), dim3(256), 0, stream>>>(
        input, head_w, proj0_w, out0_w, proj1_w, out1_w, ws, target, o3, o4, o5);

    // 2. head: [4096,1024] x [10240,1024]^T -> f32 [4096,10002]  (256^2 phase-split)
    gemm256<<<dim3(HW_ROWSP / 256, N / 256), dim3(512), 0, stream>>>(
        in_bf, hw_bf, head_out, 10002, 1024, 1024 / 64);

    // 3. merged proj: [4096,1024] x [384,1024]^T -> bf16 pp [4096,320]
    gemm_lds<0, true><<<dim3(3, N / BM), dim3(256), 0, stream>>>(
        in_bf, 1024, pjw_bf, pp, 320, 1024, nullptr);

    // 4. tail0: pp[:, :256] x out0_w^T, masked band 0 -> f32 [4096,20000]
    gemm_lds<1, false><<<dim3(O0_ROWSP / BN, N / BM), dim3(256), 0, stream>>>(
        pp, 320, o0w_bf, tail0, 20000, 256, target);

    // 5. tail1: pp[:, 256:320] x out1_w^T, masked band 1 -> f32 [4096,20000]
    gemm_lds<2, false><<<dim3(O1_ROWSP / BN, N / BM), dim3(256), 0, stream>>>(
        pp + 256, 320, o1w_bf, tail1, 20000, 64, target);
}

// Round 4
// 392.431 us; speedup vs baseline: 1.9118x; 1.0152x over previous
//
#include <hip/hip_runtime.h>

#define C0 10000
#define C1 30000
#define C2 50000

typedef __attribute__((ext_vector_type(8))) short short8;
typedef __attribute__((ext_vector_type(8))) unsigned short ushort8;
typedef __attribute__((ext_vector_type(4))) float f32x4;

__device__ __forceinline__ unsigned short f2bf(float f) {
    unsigned int u = __float_as_uint(f);
    u += 0x7FFF + ((u >> 16) & 1);   // round-to-nearest-even
    return (unsigned short)(u >> 16);
}

// ---------------- ws layout (bf16 elements) ----------------
#define SZ_IN    (4096 * 1024)
#define OFF_IN   0
#define HW_ROWSP 10240                 // 40 * 256
#define SZ_HW    (HW_ROWSP * 1024)
#define REAL_HW  (10002 * 1024)
#define OFF_HW   (OFF_IN + SZ_IN)
// merged proj weights: [384,1024]: rows 0-255 proj0_w, 256-319 proj1_w, 320-383 zero
#define OFF_PJ   (OFF_HW + SZ_HW)
#define SZ_PJ    (384 * 1024)
#define PJ_P0    (256 * 1024)
#define PJ_P1    (64 * 1024)
#define O0_ROWSP 20096                 // 157 * 128
#define SZ_O0    (O0_ROWSP * 256)
#define REAL_O0  (20000 * 256)
#define OFF_O0   (OFF_PJ + SZ_PJ)
#define O1_ROWSP 20096
#define SZ_O1    (O1_ROWSP * 64)
#define REAL_O1  (20000 * 64)
#define OFF_O1   (OFF_O0 + SZ_O0)
#define CVT_TOTAL (OFF_O1 + SZ_O1)
#define OFF_PP0C CVT_TOTAL             // compact p0 bf16 [<=4096, 256]
#define SZ_PP0C  (4096 * 256)
#define OFF_PP1C (OFF_PP0C + SZ_PP0C)  // compact p1 bf16 [<=4096, 64]
#define SZ_PP1C  (4096 * 64)
#define OFF_IDX  (OFF_PP1C + SZ_PP1C)  // int idx0[4096], idx1[4096], cnts[2]

// f32 -> bf16 conversion of all operands into ws (zero row-padding), + routing outputs.
__global__ __launch_bounds__(256) void convert_kernel(
    const float* __restrict__ in,  const float* __restrict__ hw,
    const float* __restrict__ p0w, const float* __restrict__ o0w,
    const float* __restrict__ p1w, const float* __restrict__ o1w,
    unsigned short* __restrict__ ws,
    const int* __restrict__ target,
    float* __restrict__ o3, float* __restrict__ o4, float* __restrict__ o5)
{
    long long tid = (long long)blockIdx.x * blockDim.x + threadIdx.x;
    if (tid < 4096) {
        int tg = target[tid];
        bool m0 = (tg >= C0) && (tg < C1);
        bool m1 = (tg >= C1) && (tg < C2);
        o3[tid] = (float)(m0 ? C0 : (m1 ? (C0 + 1) : tg));
        o4[tid] = (float)(m0 ? (tg - C0) : 0);
        o5[tid] = (float)(m1 ? (tg - C1) : 0);
    }
    long long i = tid * 8;
    if (i >= CVT_TOTAL) return;
    const float* src;
    long long rel, real;
    if (i < OFF_HW)                 { src = in;  rel = i - OFF_IN;              real = SZ_IN;   }
    else if (i < OFF_PJ)            { src = hw;  rel = i - OFF_HW;              real = REAL_HW; }
    else if (i < OFF_PJ + PJ_P0)    { src = p0w; rel = i - OFF_PJ;              real = PJ_P0;   }
    else if (i < OFF_PJ + PJ_P0 + PJ_P1) { src = p1w; rel = i - (OFF_PJ + PJ_P0); real = PJ_P1; }
    else if (i < OFF_O0)            { src = p1w; rel = 1;                       real = 0;       }
    else if (i < OFF_O1)            { src = o0w; rel = i - OFF_O0;              real = REAL_O0; }
    else                            { src = o1w; rel = i - OFF_O1;              real = REAL_O1; }
    ushort8 o;
    if (rel < real) {
        float4 v0 = *(const float4*)(src + rel);
        float4 v1 = *(const float4*)(src + rel + 4);
        o[0] = f2bf(v0.x); o[1] = f2bf(v0.y); o[2] = f2bf(v0.z); o[3] = f2bf(v0.w);
        o[4] = f2bf(v1.x); o[5] = f2bf(v1.y); o[6] = f2bf(v1.z); o[7] = f2bf(v1.w);
    } else {
        o = (ushort8)0;
    }
    *(ushort8*)(ws + i) = o;
}

// Deterministic stable compaction of band-0/band-1 row indices (one block).
__global__ __launch_bounds__(1024) void build_idx(const int* __restrict__ target,
                                                  int* __restrict__ idx0,
                                                  int* __restrict__ idx1,
                                                  int* __restrict__ cnts)
{
    __shared__ int wsum0[16], wsum1[16];
    __shared__ int base0, base1;
    const int t = threadIdx.x, lane = t & 63, wv = t >> 6;
    if (t == 0) { base0 = 0; base1 = 0; }
    __syncthreads();
    for (int r = 0; r < 4; r++) {
        int i = r * 1024 + t;
        int tg = target[i];
        bool p0 = (tg >= C0) && (tg < C1);
        bool p1 = (tg >= C1) && (tg < C2);
        unsigned long long b0 = __ballot(p0);
        unsigned long long b1 = __ballot(p1);
        int pre0 = __popcll(b0 & ((1ull << lane) - 1));
        int pre1 = __popcll(b1 & ((1ull << lane) - 1));
        if (lane == 0) { wsum0[wv] = __popcll(b0); wsum1[wv] = __popcll(b1); }
        __syncthreads();
        int woff0 = base0, woff1 = base1;
        for (int k = 0; k < wv; k++) { woff0 += wsum0[k]; woff1 += wsum1[k]; }
        if (p0) idx0[woff0 + pre0] = i;
        if (p1) idx1[woff1 + pre1] = i;
        __syncthreads();
        if (t == 0) {
            for (int k = 0; k < 16; k++) { base0 += wsum0[k]; base1 += wsum1[k]; }
        }
        __syncthreads();
    }
    for (int j = base0 + t; j < 4096; j += 1024) idx0[j] = 0;   // pad for safe gather
    for (int j = base1 + t; j < 4096; j += 1024) idx1[j] = 0;
    if (t == 0) { cnts[0] = base0; cnts[1] = base1; }
}

// Stream zeros into non-band rows of tail0/tail1 (float4, near-peak write BW).
__global__ __launch_bounds__(256) void fill_nonband(
    const int* __restrict__ target,
    float* __restrict__ tail0, float* __restrict__ tail1)
{
    int row   = blockIdx.x >> 1;
    int which = blockIdx.x & 1;
    int tg = target[row];
    bool in = which ? (tg >= C1 && tg < C2) : (tg >= C0 && tg < C1);
    if (in) return;
    float4* dst = (float4*)((which ? tail1 : tail0) + (size_t)row * 20000);
    float4 z = {0.f, 0.f, 0.f, 0.f};
    for (int i = threadIdx.x; i < 5000; i += 256) dst[i] = z;
}

// ================= 256x256 8-wave phase-split GEMM (head) =================
__device__ __forceinline__ short8 lds_read_swz(const unsigned short* base, int row, int chunk) {
    int slot = chunk ^ (row & 7);
    return *(const short8*)(base + row * 64 + slot * 8);
}

#define PHASE(MO, NO, LOADA)                                                   \
  {                                                                            \
    if (LOADA) {                                                               \
      _Pragma("unroll") for (int m = 0; m < 4; m++)                            \
        _Pragma("unroll") for (int ks = 0; ks < 2; ks++)                       \
          af[m][ks] = lds_read_swz(Ab, (MO + m) * 16 + lr, ks * 4 + lq);       \
    }                                                                          \
    _Pragma("unroll") for (int n = 0; n < 2; n++)                              \
      _Pragma("unroll") for (int ks = 0; ks < 2; ks++)                         \
        bfrag[n][ks] = lds_read_swz(Bb, brow0 + (NO + n) * 16 + lr, ks * 4 + lq); \
    __builtin_amdgcn_s_barrier();                                              \
    asm volatile("s_waitcnt lgkmcnt(0)" ::: "memory");                         \
    __builtin_amdgcn_sched_barrier(0);                                         \
    __builtin_amdgcn_s_setprio(1);                                             \
    _Pragma("unroll") for (int m = 0; m < 4; m++)                              \
      _Pragma("unroll") for (int n = 0; n < 2; n++)                            \
        _Pragma("unroll") for (int ks = 0; ks < 2; ks++)                       \
          acc[MO + m][NO + n] = __builtin_amdgcn_mfma_f32_16x16x32_bf16(       \
              af[m][ks], bfrag[n][ks], acc[MO + m][NO + n], 0, 0, 0);          \
    __builtin_amdgcn_s_setprio(0);                                             \
    __builtin_amdgcn_s_barrier();                                              \
  }

#define STAGE(bufi, kofs)                                                      \
  {                                                                            \
    _Pragma("unroll") for (int hh = 0; hh < 2; hh++)                           \
      _Pragma("unroll") for (int cc = 0; cc < 2; cc++) {                       \
        __builtin_amdgcn_global_load_lds(                                      \
            (const __attribute__((address_space(1))) void*)(srcA[hh][cc] + (kofs)), \
            (__attribute__((address_space(3))) void*)(lds + (bufi) * 32768 +   \
                hh * 8192 + (cc * 64 + w * 8) * 64), 16, 0, 0);                \
        __builtin_amdgcn_global_load_lds(                                      \
            (const __attribute__((address_space(1))) void*)(srcB[hh][cc] + (kofs)), \
            (__attribute__((address_space(3))) void*)(lds + (bufi) * 32768 +   \
                16384 + hh * 8192 + (cc * 64 + w * 8) * 64), 16, 0, 0);        \
      }                                                                        \
  }

__global__ __launch_bounds__(512) void gemm256(
    const unsigned short* __restrict__ A,
    const unsigned short* __restrict__ B,
    float* __restrict__ C, int Nn, int K, int NT)
{
    __shared__ unsigned short lds[65536];   // 128 KB

    const int t    = threadIdx.x;
    const int lane = t & 63;
    const int w    = t >> 6;
    const int wm   = w >> 2;
    const int wn   = w & 3;
    const int lr   = lane & 15;
    const int lq   = lane >> 4;
    const int brow0 = (wn & 1) * 64;

    const int mBase = blockIdx.y * 256;
    const int nBase = blockIdx.x * 256;

    const int lr3 = lane >> 3;
    const int swzc = ((lane & 7) ^ lr3) * 8;
    const unsigned short* srcA[2][2];
    const unsigned short* srcB[2][2];
    #pragma unroll
    for (int hh = 0; hh < 2; hh++)
        #pragma unroll
        for (int cc = 0; cc < 2; cc++) {
            int rrow = hh * 128 + cc * 64 + w * 8 + lr3;
            srcA[hh][cc] = A + (size_t)(mBase + rrow) * K + swzc;
            srcB[hh][cc] = B + (size_t)(nBase + rrow) * K + swzc;
        }

    f32x4 acc[8][4] = {};
    short8 af[4][2], bfrag[2][2];

    STAGE(0, 0);
    for (int kt = 0; kt < NT; ++kt) {
        const int buf = kt & 1;
        STAGE(buf ^ 1, (kt + 1) * 64);
        asm volatile("s_waitcnt vmcnt(8)" ::: "memory");
        __builtin_amdgcn_s_barrier();
        const unsigned short* Ab = lds + buf * 32768 + wm * 8192;
        const unsigned short* Bb = lds + buf * 32768 + 16384 + (wn >> 1) * 8192;
        PHASE(0, 0, 1)
        PHASE(0, 2, 0)
        PHASE(4, 0, 1)
        PHASE(4, 2, 0)
    }

    #pragma unroll
    for (int m = 0; m < 8; m++) {
        #pragma unroll
        for (int i = 0; i < 4; i++) {
            int grow = mBase + wm * 128 + m * 16 + lq * 4 + i;
            #pragma unroll
            for (int n = 0; n < 4; n++) {
                int gcol = nBase + wn * 64 + n * 16 + lr;
                if (gcol < Nn)
                    C[(size_t)grow * Nn + gcol] = acc[m][n][i];
            }
        }
    }
}

// ================= 128x128 compacted GEMMs =================
#define BM 128
#define BN 128
#define BK 64

// pp_c[local_row, :] = input[idx[local_row], :] @ W^T   (gathered A, linear bf16 store)
__global__ __launch_bounds__(256) void proj_gather(
    const unsigned short* __restrict__ A,   // in_bf [4096,1024]
    const unsigned short* __restrict__ B,   // weights [>=128 rows padded, K]
    unsigned short* __restrict__ Cb,        // ppc [4096, Nn]
    int Nn, int K,
    const int* __restrict__ idx, const int* __restrict__ cntp)
{
    const int cnt = *cntp;
    const int mBase = blockIdx.y * BM;
    if (mBase >= cnt) return;

    __shared__ unsigned short As[BM * BK];
    __shared__ unsigned short Bs[BN * BK];

    const int t    = threadIdx.x;
    const int lane = t & 63;
    const int w    = t >> 6;
    const int wr   = w >> 1;
    const int wc   = w & 1;
    const int nBase = blockIdx.x * BN;
    const int srow = lane >> 3;
    const int scol = (lane & 7) * 8;

    int rowsIdx[4];
    #pragma unroll
    for (int c = 0; c < 4; c++)
        rowsIdx[c] = idx[mBase + w * 32 + c * 8 + srow];

    f32x4 acc[4][4] = {};

    for (int k0 = 0; k0 < K; k0 += BK) {
        #pragma unroll
        for (int c = 0; c < 4; c++) {
            const int rbase = w * 32 + c * 8;
            const unsigned short* ga = A + (size_t)rowsIdx[c] * K + k0 + scol;
            __builtin_amdgcn_global_load_lds(
                (const __attribute__((address_space(1))) void*)ga,
                (__attribute__((address_space(3))) void*)&As[rbase * BK], 16, 0, 0);
            const unsigned short* gb = B + (size_t)(nBase + rbase + srow) * K + k0 + scol;
            __builtin_amdgcn_global_load_lds(
                (const __attribute__((address_space(1))) void*)gb,
                (__attribute__((address_space(3))) void*)&Bs[rbase * BK], 16, 0, 0);
        }
        __syncthreads();

        #pragma unroll
        for (int kk = 0; kk < BK / 32; kk++) {
            const int kOff = kk * 32 + (lane >> 4) * 8;
            short8 a4[4], b4[4];
            #pragma unroll
            for (int m = 0; m < 4; m++)
                a4[m] = *(const short8*)(&As[(wr * 64 + m * 16 + (lane & 15)) * BK + kOff]);
            #pragma unroll
            for (int n = 0; n < 4; n++)
                b4[n] = *(const short8*)(&Bs[(wc * 64 + n * 16 + (lane & 15)) * BK + kOff]);
            #pragma unroll
            for (int m = 0; m < 4; m++)
                #pragma unroll
                for (int n = 0; n < 4; n++)
                    acc[m][n] = __builtin_amdgcn_mfma_f32_16x16x32_bf16(
                        a4[m], b4[n], acc[m][n], 0, 0, 0);
        }
        __syncthreads();
    }

    #pragma unroll
    for (int m = 0; m < 4; m++)
        #pragma unroll
        for (int i = 0; i < 4; i++) {
            int grow = mBase + wr * 64 + m * 16 + (lane >> 4) * 4 + i;
            #pragma unroll
            for (int n = 0; n < 4; n++) {
                int gcol = nBase + wc * 64 + n * 16 + (lane & 15);
                if (gcol < Nn)
                    Cb[(size_t)grow * Nn + gcol] = f2bf(acc[m][n][i]);
            }
        }
}

// Out[idx[lr], :] = ppc[lr, :] @ W^T  for lr < cnt   (linear A, scattered f32 store)
__global__ __launch_bounds__(256) void tail_scatter(
    const unsigned short* __restrict__ A,   // ppc [4096, K]
    const unsigned short* __restrict__ B,   // weights [padded rows, K]
    float* __restrict__ Out,                // [4096, 20000]
    int K,
    const int* __restrict__ idx, const int* __restrict__ cntp)
{
    const int cnt = *cntp;
    const int mBase = blockIdx.y * BM;
    if (mBase >= cnt) return;

    __shared__ unsigned short As[BM * BK];
    __shared__ unsigned short Bs[BN * BK];

    const int t    = threadIdx.x;
    const int lane = t & 63;
    const int w    = t >> 6;
    const int wr   = w >> 1;
    const int wc   = w & 1;
    const int nBase = blockIdx.x * BN;
    const int srow = lane >> 3;
    const int scol = (lane & 7) * 8;

    f32x4 acc[4][4] = {};

    for (int k0 = 0; k0 < K; k0 += BK) {
        #pragma unroll
        for (int c = 0; c < 4; c++) {
            const int rbase = w * 32 + c * 8;
            const unsigned short* ga = A + (size_t)(mBase + rbase + srow) * K + k0 + scol;
            __builtin_amdgcn_global_load_lds(
                (const __attribute__((address_space(1))) void*)ga,
                (__attribute__((address_space(3))) void*)&As[rbase * BK], 16, 0, 0);
            const unsigned short* gb = B + (size_t)(nBase + rbase + srow) * K + k0 + scol;
            __builtin_amdgcn_global_load_lds(
                (const __attribute__((address_space(1))) void*)gb,
                (__attribute__((address_space(3))) void*)&Bs[rbase * BK], 16, 0, 0);
        }
        __syncthreads();

        #pragma unroll
        for (int kk = 0; kk < BK / 32; kk++) {
            const int kOff = kk * 32 + (lane >> 4) * 8;
            short8 a4[4], b4[4];
            #pragma unroll
            for (int m = 0; m < 4; m++)
                a4[m] = *(const short8*)(&As[(wr * 64 + m * 16 + (lane & 15)) * BK + kOff]);
            #pragma unroll
            for (int n = 0; n < 4; n++)
                b4[n] = *(const short8*)(&Bs[(wc * 64 + n * 16 + (lane & 15)) * BK + kOff]);
            #pragma unroll
            for (int m = 0; m < 4; m++)
                #pragma unroll
                for (int n = 0; n < 4; n++)
                    acc[m][n] = __builtin_amdgcn_mfma_f32_16x16x32_bf16(
                        a4[m], b4[n], acc[m][n], 0, 0, 0);
        }
        __syncthreads();
    }

    #pragma unroll
    for (int m = 0; m < 4; m++)
        #pragma unroll
        for (int i = 0; i < 4; i++) {
            int grow_local = mBase + wr * 64 + m * 16 + (lane >> 4) * 4 + i;
            if (grow_local < cnt) {
                int gr = idx[grow_local];
                #pragma unroll
                for (int n = 0; n < 4; n++) {
                    int gcol = nBase + wc * 64 + n * 16 + (lane & 15);
                    if (gcol < 20000)
                        Out[(size_t)gr * 20000 + gcol] = acc[m][n][i];
                }
            }
        }
}

extern "C" void kernel_launch(void* const* d_in, const int* in_sizes, int n_in,
                              void* d_out, int out_size, void* d_ws, size_t ws_size,
                              hipStream_t stream)
{
    const float* input   = (const float*)d_in[0];
    const int*   target  = (const int*)  d_in[1];
    const float* head_w  = (const float*)d_in[2];
    const float* proj0_w = (const float*)d_in[3];
    const float* out0_w  = (const float*)d_in[4];
    const float* proj1_w = (const float*)d_in[5];
    const float* out1_w  = (const float*)d_in[6];

    const int N = 4096;

    float* out      = (float*)d_out;
    float* head_out = out;
    float* tail0    = head_out + (size_t)N * 10002;
    float* tail1    = tail0 + (size_t)N * 20000;
    float* o3       = tail1 + (size_t)N * 20000;
    float* o4       = o3 + N;
    float* o5       = o4 + N;

    unsigned short* ws = (unsigned short*)d_ws;
    unsigned short* in_bf  = ws + OFF_IN;
    unsigned short* hw_bf  = ws + OFF_HW;
    unsigned short* pjw_bf = ws + OFF_PJ;
    unsigned short* o0w_bf = ws + OFF_O0;
    unsigned short* o1w_bf = ws + OFF_O1;
    unsigned short* pp0c   = ws + OFF_PP0C;
    unsigned short* pp1c   = ws + OFF_PP1C;
    int* idx0 = (int*)(ws + OFF_IDX);
    int* idx1 = idx0 + 4096;
    int* cnts = idx1 + 4096;

    // 1. convert all operands to bf16 (zero-padded) + routing outputs
    convert_kernel<<<dim3(CVT_TOTAL / 8 / 256), dim3(256), 0, stream>>>(
        input, head_w, proj0_w, out0_w, proj1_w, out1_w, ws, target, o3, o4, o5);

    // 2. band-row index compaction (deterministic)
    build_idx<<<dim3(1), dim3(1024), 0, stream>>>(target, idx0, idx1, cnts);

    // 3. head: [4096,1024] x [10240,1024]^T -> f32 [4096,10002]
    gemm256<<<dim3(HW_ROWSP / 256, N / 256), dim3(512), 0, stream>>>(
        in_bf, hw_bf, head_out, 10002, 1024, 1024 / 64);

    // 4. zero-fill non-band rows of both tails (streaming float4)
    fill_nonband<<<dim3(2 * N), dim3(256), 0, stream>>>(target, tail0, tail1);

    // 5. compacted projections (gathered A rows)
    proj_gather<<<dim3(2, N / BM), dim3(256), 0, stream>>>(
        in_bf, pjw_bf, pp0c, 256, 1024, idx0, cnts);
    proj_gather<<<dim3(1, N / BM), dim3(256), 0, stream>>>(
        in_bf, pjw_bf + 256 * 1024, pp1c, 64, 1024, idx1, cnts + 1);

    // 6. compacted tails (linear A, scattered row writes)
    tail_scatter<<<dim3(O0_ROWSP / BN, N / BM), dim3(256), 0, stream>>>(
        pp0c, o0w_bf, tail0, 256, idx0, cnts);
    tail_scatter<<<dim3(O1_ROWSP / BN, N / BM), dim3(256), 0, stream>>>(
        pp1c, o1w_bf, tail1, 64, idx1, cnts + 1);
}